// Round 2
// baseline (571.467 us; speedup 1.0000x reference)
//
#include <hip/hip_runtime.h>
#include <hip/hip_bf16.h>
#include <stdint.h>

// ---------------------------------------------------------------------------
// SupervisedTEMTransition: logits = clip(g + routed_transition(g), +-1) @ W^T + b
//   B=16384, G_TOTAL=768 (modules 256,256,128,128), A=4, NUM_STATES=4096
// R2: action-bucketed transition. Rows are counting-sorted by action; one
// merged transition GEMM launch computes ONLY the matching D_a block per row
// segment (1x FLOP instead of 4x compute-and-discard), eliminating 3 launches.
// GEMM core (both GEMMs): 128x128 tile, BK=64, mfma_f32_16x16x32_bf16,
// 4 waves (2x2), 4x4 float4 acc, global_load_lds width=16, XOR-swizzled LDS.
// ---------------------------------------------------------------------------

typedef __attribute__((ext_vector_type(8))) short short8;   // 8 x bf16
typedef __attribute__((ext_vector_type(4))) float floatx4;  // MFMA C/D

__device__ __forceinline__ float bf2f(short s) {
    unsigned int u = ((unsigned int)(unsigned short)s) << 16;
    float f;
    __builtin_memcpy(&f, &u, 4);
    return f;
}
__device__ __forceinline__ short f2bf(float f) {  // round-to-nearest-even
    unsigned int u;
    __builtin_memcpy(&u, &f, 4);
    u = (u + 0x7FFFu + ((u >> 16) & 1u)) >> 16;
    return (short)u;
}

#define GLLDS16(g, l)                                                                     \
    __builtin_amdgcn_global_load_lds((const __attribute__((address_space(1))) void*)(g),  \
                                     (__attribute__((address_space(3))) void*)(l), 16, 0, 0)

// meta layout (ints): [0..3]=cnt  [4..7]=off  [8..12]=tilestart[0..4]  [13..16]=cursor

// ---------------------------------------------------------------------------
// prep: one float4 per thread (regions: A1 gather | W_cls | D0..D3), plus
// block 0 zeroes the bucket counters for the counting sort.
// ---------------------------------------------------------------------------
__global__ __launch_bounds__(256) void prep_kernel(
    const int* __restrict__ state, const float* __restrict__ emb,
    const float* __restrict__ W, const float* __restrict__ D0,
    const float* __restrict__ D1, const float* __restrict__ D2,
    const float* __restrict__ D3, short* __restrict__ A1,
    short* __restrict__ Wb, short* __restrict__ Db, int* __restrict__ meta) {
    if (blockIdx.x == 0 && threadIdx.x < 4) meta[threadIdx.x] = 0;
    long e = (long)blockIdx.x * 256 + threadIdx.x;
    const float* src;
    short* dst;
    long di;
    if (e < 3145728L) {
        int b = (int)(e / 192);
        int cc = (int)(e % 192);
        int s = state[b];
        src = emb + (long)s * 768 + cc * 4;
        dst = A1; di = e;
    } else if (e < 3932160L) {
        long t = e - 3145728L;
        src = W + t * 4; dst = Wb; di = t;
    } else if (e < 3997696L) {
        long t = e - 3932160L;
        src = D0 + t * 4; dst = Db; di = t;
    } else if (e < 4063232L) {
        long t = e - 3997696L;
        src = D1 + t * 4; dst = Db + 262144; di = t;
    } else if (e < 4079616L) {
        long t = e - 4063232L;
        src = D2 + t * 4; dst = Db + 524288; di = t;
    } else {
        long t = e - 4079616L;
        src = D3 + t * 4; dst = Db + 589824; di = t;
    }
    float4 v = *(const float4*)src;
    union { ushort4 u4; short s4[4]; } o;
    o.s4[0] = f2bf(v.x); o.s4[1] = f2bf(v.y);
    o.s4[2] = f2bf(v.z); o.s4[3] = f2bf(v.w);
    *(ushort4*)(dst + di * 4) = o.u4;
}

// ---------------------------------------------------------------------------
// counting sort of rows by action
// ---------------------------------------------------------------------------
__global__ __launch_bounds__(256) void count_kernel(const int* __restrict__ act,
                                                    int* __restrict__ meta) {
    __shared__ int lc[4];
    if (threadIdx.x < 4) lc[threadIdx.x] = 0;
    __syncthreads();
    int i = blockIdx.x * 256 + threadIdx.x;
    atomicAdd(&lc[act[i]], 1);
    __syncthreads();
    if (threadIdx.x < 4) atomicAdd(&meta[threadIdx.x], lc[threadIdx.x]);
}

__global__ void scan_kernel(int* __restrict__ meta) {
    if (threadIdx.x == 0) {
        int o = 0, t = 0;
        meta[8] = 0;                       // tilestart[0]
        for (int a = 0; a < 4; ++a) {
            meta[4 + a] = o;               // off
            meta[13 + a] = o;              // cursor
            o += meta[a];
            t += (meta[a] + 127) >> 7;
            meta[9 + a] = t;               // tilestart[a+1]; meta[12] = total tiles
        }
    }
}

__global__ __launch_bounds__(256) void scatter_kernel(const int* __restrict__ act,
                                                      int* __restrict__ meta,
                                                      int* __restrict__ rowidx) {
    int i = blockIdx.x * 256 + threadIdx.x;
    int a = act[i];
    int slot = atomicAdd(&meta[13 + a], 1);
    rowidx[slot] = i;
}

// ---------------------------------------------------------------------------
// Merged transition GEMM over bucketed rows.
// Grid x = 6 (module,coltile) slots: {(m0,c0),(m0,c1),(m1,c0),(m1,c1),(m2,c0),(m3,c0)}
// Grid y = 131 row-tile slots (worst case: 16384/128 + 3).
// delta[b,j] = sum_i D[a, j, i] * g[b, i];  g_next = clip(g + delta, +-1)
// ---------------------------------------------------------------------------
__global__ __launch_bounds__(256) void trans_gemm_kernel(
    const short* __restrict__ A1, const short* __restrict__ Db,
    const int* __restrict__ meta, const int* __restrict__ rowidx,
    float* __restrict__ gnext, short* __restrict__ A2) {
    __shared__ short Ash[128 * 64];
    __shared__ short Bsh[128 * 64];
    __shared__ int ridx[128];
    const int ty = blockIdx.y;
    if (ty >= meta[12]) return;            // block-uniform early exit
    int a = 0;
    #pragma unroll
    for (int i = 1; i < 4; ++i)
        if (ty >= meta[8 + i]) a = i;
    const int rtile = ty - meta[8 + a];
    const int cnt   = meta[a];
    const int off   = meta[4 + a];
    const int cval  = min(128, cnt - rtile * 128);   // valid rows in this tile

    const int slot = blockIdx.x;
    const int mod  = slot < 4 ? (slot >> 1) : slot - 2;
    const int colt = slot < 4 ? (slot & 1) : 0;
    const int n    = mod < 2 ? 256 : 128;
    const int aoff = mod < 2 ? mod * 256 : 512 + (mod - 2) * 128;
    const long doff = mod == 0 ? 0L : mod == 1 ? 262144L : mod == 2 ? 524288L : 589824L;
    const short* Bm = Db + doff + ((long)a * n + colt * 128) * n;

    const int tid = threadIdx.x;
    if (tid < 128) ridx[tid] = rowidx[off + rtile * 128 + min(tid, cval - 1)];
    __syncthreads();

    const int lane = tid & 63;
    const int w = tid >> 6;
    const int wm = w & 1, wn = w >> 1;
    const int lrow = lane & 15;
    const int q = lane >> 4;

    floatx4 acc[4][4] = {};

    for (int k0 = 0; k0 < n; k0 += 64) {
        #pragma unroll
        for (int it = 0; it < 4; ++it) {
            int c = it * 256 + tid;        // 16B chunk: row = c/8, kchunk = c%8
            int r = c >> 3, cc = c & 7;
            int gc = cc ^ (r & 7);         // XOR swizzle
            int row = ridx[r];
            GLLDS16(A1 + (long)row * 768 + aoff + k0 + gc * 8, &Ash[c * 8]);
            GLLDS16(Bm + (long)r * n + k0 + gc * 8, &Bsh[c * 8]);
        }
        __syncthreads();
        #pragma unroll
        for (int kk = 0; kk < 2; ++kk) {
            short8 af[4], bv[4];
            #pragma unroll
            for (int mi = 0; mi < 4; ++mi) {
                int rr = wm * 64 + mi * 16 + lrow;
                int ch = (kk * 4 + q) ^ (rr & 7);
                af[mi] = *(const short8*)&Ash[rr * 64 + ch * 8];
            }
            #pragma unroll
            for (int ni = 0; ni < 4; ++ni) {
                int rr = wn * 64 + ni * 16 + lrow;
                int ch = (kk * 4 + q) ^ (rr & 7);
                bv[ni] = *(const short8*)&Bsh[rr * 64 + ch * 8];
            }
            #pragma unroll
            for (int mi = 0; mi < 4; ++mi)
                #pragma unroll
                for (int ni = 0; ni < 4; ++ni)
                    acc[mi][ni] = __builtin_amdgcn_mfma_f32_16x16x32_bf16(
                        af[mi], bv[ni], acc[mi][ni], 0, 0, 0);
        }
        __syncthreads();
    }

    const int jb = colt * 128 + wn * 64;   // module-local col base
    #pragma unroll
    for (int mi = 0; mi < 4; ++mi) {
        #pragma unroll
        for (int r4 = 0; r4 < 4; ++r4) {
            int local = wm * 64 + mi * 16 + q * 4 + r4;
            if (local < cval) {
                int row = ridx[local];
                #pragma unroll
                for (int ni = 0; ni < 4; ++ni) {
                    int jl = jb + ni * 16 + lrow;
                    long idx = (long)row * 768 + aoff + jl;
                    float g = bf2f(A1[idx]);
                    float v = g + acc[mi][ni][r4];
                    v = fminf(1.0f, fmaxf(-1.0f, v));
                    gnext[idx] = v;
                    A2[idx] = f2bf(v);
                }
            }
        }
    }
}

// ---------------------------------------------------------------------------
// Classifier GEMM: [16384x768] @ [4096x768]^T + bias -> fp32. Grid (32, 128).
// ---------------------------------------------------------------------------
__global__ __launch_bounds__(256) void cls_gemm_kernel(
    const short* __restrict__ A, const short* __restrict__ Bm,
    const float* __restrict__ bias, float* __restrict__ out) {
    __shared__ short Ash[128 * 64];
    __shared__ short Bsh[128 * 64];
    const int tid = threadIdx.x;
    const int lane = tid & 63;
    const int w = tid >> 6;
    const int wm = w & 1, wn = w >> 1;
    const int bn = blockIdx.x, bm = blockIdx.y;
    const long arow0 = (long)bm * 128;
    const long brow0 = (long)bn * 128;
    const int lrow = lane & 15;
    const int q = lane >> 4;

    floatx4 acc[4][4] = {};

    for (int k0 = 0; k0 < 768; k0 += 64) {
        #pragma unroll
        for (int it = 0; it < 4; ++it) {
            int c = it * 256 + tid;
            int r = c >> 3, cc = c & 7;
            int gc = cc ^ (r & 7);
            GLLDS16(A + (arow0 + r) * 768 + k0 + gc * 8, &Ash[c * 8]);
            GLLDS16(Bm + (brow0 + r) * 768 + k0 + gc * 8, &Bsh[c * 8]);
        }
        __syncthreads();
        #pragma unroll
        for (int kk = 0; kk < 2; ++kk) {
            short8 af[4], bv[4];
            #pragma unroll
            for (int mi = 0; mi < 4; ++mi) {
                int rr = wm * 64 + mi * 16 + lrow;
                int ch = (kk * 4 + q) ^ (rr & 7);
                af[mi] = *(const short8*)&Ash[rr * 64 + ch * 8];
            }
            #pragma unroll
            for (int ni = 0; ni < 4; ++ni) {
                int rr = wn * 64 + ni * 16 + lrow;
                int ch = (kk * 4 + q) ^ (rr & 7);
                bv[ni] = *(const short8*)&Bsh[rr * 64 + ch * 8];
            }
            #pragma unroll
            for (int mi = 0; mi < 4; ++mi)
                #pragma unroll
                for (int ni = 0; ni < 4; ++ni)
                    acc[mi][ni] = __builtin_amdgcn_mfma_f32_16x16x32_bf16(
                        af[mi], bv[ni], acc[mi][ni], 0, 0, 0);
        }
        __syncthreads();
    }

    const int rowbase = bm * 128 + wm * 64;
    const int colbase = bn * 128 + wn * 64;
    #pragma unroll
    for (int mi = 0; mi < 4; ++mi) {
        #pragma unroll
        for (int r = 0; r < 4; ++r) {
            int row = rowbase + mi * 16 + q * 4 + r;
            #pragma unroll
            for (int ni = 0; ni < 4; ++ni) {
                int col = colbase + ni * 16 + lrow;
                out[(long)row * 4096 + col] = acc[mi][ni][r] + bias[col];
            }
        }
    }
}

extern "C" void kernel_launch(void* const* d_in, const int* in_sizes, int n_in,
                              void* d_out, int out_size, void* d_ws, size_t ws_size,
                              hipStream_t stream) {
    const int* state  = (const int*)d_in[0];
    const int* act    = (const int*)d_in[1];
    const float* emb  = (const float*)d_in[2];
    const float* W    = (const float*)d_in[3];
    const float* bias = (const float*)d_in[4];
    const float* D0   = (const float*)d_in[5];
    const float* D1   = (const float*)d_in[6];
    const float* D2   = (const float*)d_in[7];
    const float* D3   = (const float*)d_in[8];

    float* logits = (float*)d_out;              // [16384 x 4096]
    float* gnext  = logits + 67108864L;         // [16384 x 768]

    short* A1 = (short*)d_ws;                   // g bf16        [16384 x 768]
    short* A2 = A1 + 12582912L;                 // g_next bf16   [16384 x 768]
    short* Wb = A2 + 12582912L;                 // W_cls bf16    [4096 x 768]
    short* Db = Wb + 3145728L;                  // D0|D1|D2|D3 bf16 (655360)
    int*   meta   = (int*)(Db + 655360);        // 17 ints (pad to 32)
    int*   rowidx = meta + 32;                  // [16384]

    prep_kernel<<<16000, 256, 0, stream>>>(state, emb, W, D0, D1, D2, D3, A1, Wb, Db, meta);
    count_kernel<<<64, 256, 0, stream>>>(act, meta);
    scan_kernel<<<1, 64, 0, stream>>>(meta);
    scatter_kernel<<<64, 256, 0, stream>>>(act, meta, rowidx);
    trans_gemm_kernel<<<dim3(6, 131), 256, 0, stream>>>(A1, Db, meta, rowidx, gnext, A2);
    cls_gemm_kernel<<<dim3(32, 128), 256, 0, stream>>>(A2, Wb, bias, logits);
}